// Round 2
// baseline (185.837 us; speedup 1.0000x reference)
//
#include <hip/hip_runtime.h>
#include <math.h>

#define NN 16777216
#define KBINS 5
#define TBOUND 2.5f

// Per-bin tables packed for single ds_read_b128 lookups:
//   t0[b] = { cw[b],  1/(cw[b+1]-cw[b]+1e-8),  s_k=H/W,  2*log(s_k+1e-8) }
//   t1[b] = { ch[b],  ch[b+1]-ch[b],           D[b],     D[b+1]          }

__device__ __forceinline__ void rqs1(float x,
                                     float c1, float c2, float c3, float c4,
                                     const float4* __restrict__ t0,
                                     const float4* __restrict__ t1,
                                     float& z, float& lj) {
    bool inside = (x >= -TBOUND) && (x <= TBOUND);
    float xs = inside ? x : 0.0f;
    // searchsorted(cum_w[1:-1], xs, 'left') == count of boundaries < xs
    int b = (int)(xs > c1) + (int)(xs > c2) + (int)(xs > c3) + (int)(xs > c4);
    float4 a  = t0[b];
    float4 cc = t1[b];
    float xi = (xs - a.x) * a.y;
    xi = fminf(fmaxf(xi, 0.0f), 1.0f);
    float omxi = 1.0f - xi;
    float xo   = xi * omxi;
    float sk = a.z;
    float dk = cc.z, dk1 = cc.w;
    float denom = fmaf(dk + dk1 - 2.0f * sk, xo, sk);
    float num   = fmaf(sk * xi, xi, dk * xo);
    float zin   = fmaf(cc.y, num / (denom + 1e-8f), cc.x);
    float numj  = fmaf(dk1 * xi, xi, fmaf(2.0f * sk, xo, dk * omxi * omxi));
    float ljin  = a.w + __logf(numj + 1e-8f) - 2.0f * __logf(fabsf(denom) + 1e-8f);
    z  = inside ? zin  : x;
    lj = inside ? ljin : 0.0f;
}

__global__ __launch_bounds__(256) void rqs_kernel(const float* __restrict__ x,
                                                  const float* __restrict__ params,
                                                  float* __restrict__ out) {
    __shared__ float4 t0[KBINS];
    __shared__ float4 t1[KBINS];
    __shared__ float  cwS[KBINS + 1];

    if (threadIdx.x == 0) {
        float p[3 * KBINS + 1];
        #pragma unroll
        for (int i = 0; i < 3 * KBINS + 1; ++i) p[i] = params[i];

        // softmax(widths) * 2*TB
        float mw = p[0];
        #pragma unroll
        for (int i = 1; i < KBINS; ++i) mw = fmaxf(mw, p[i]);
        float ew[KBINS]; float sw = 0.0f;
        #pragma unroll
        for (int i = 0; i < KBINS; ++i) { ew[i] = __expf(p[i] - mw); sw += ew[i]; }
        float W[KBINS];
        #pragma unroll
        for (int i = 0; i < KBINS; ++i) W[i] = ew[i] / sw * (2.0f * TBOUND);

        // softmax(heights) * 2*TB
        float mh = p[KBINS];
        #pragma unroll
        for (int i = 1; i < KBINS; ++i) mh = fmaxf(mh, p[KBINS + i]);
        float eh[KBINS]; float sh = 0.0f;
        #pragma unroll
        for (int i = 0; i < KBINS; ++i) { eh[i] = __expf(p[KBINS + i] - mh); sh += eh[i]; }
        float H[KBINS];
        #pragma unroll
        for (int i = 0; i < KBINS; ++i) H[i] = eh[i] / sh * (2.0f * TBOUND);

        // softplus(derivs) + 1e-5  (numerically safe form)
        float D[KBINS + 1];
        #pragma unroll
        for (int i = 0; i < KBINS + 1; ++i) {
            float v = p[2 * KBINS + i];
            D[i] = fmaxf(v, 0.0f) + log1pf(__expf(-fabsf(v))) + 1e-5f;
        }

        // cumulative knots
        float cw[KBINS + 1], ch[KBINS + 1];
        cw[0] = -TBOUND; ch[0] = -TBOUND;
        float aw = 0.0f, ah = 0.0f;
        #pragma unroll
        for (int i = 0; i < KBINS; ++i) {
            aw += W[i]; cw[i + 1] = -TBOUND + aw;
            ah += H[i]; ch[i + 1] = -TBOUND + ah;
        }

        #pragma unroll
        for (int b = 0; b < KBINS; ++b) {
            float sk = H[b] / W[b];
            t0[b] = make_float4(cw[b],
                                1.0f / (cw[b + 1] - cw[b] + 1e-8f),
                                sk,
                                2.0f * logf(sk + 1e-8f));
            t1[b] = make_float4(ch[b], ch[b + 1] - ch[b], D[b], D[b + 1]);
        }
        #pragma unroll
        for (int i = 0; i < KBINS + 1; ++i) cwS[i] = cw[i];
    }
    __syncthreads();

    // loop-invariant interior boundaries → registers
    float c1 = cwS[1], c2 = cwS[2], c3 = cwS[3], c4 = cwS[4];

    const float4* __restrict__ xv  = (const float4*)x;
    float4* __restrict__ zv  = (float4*)out;
    float4* __restrict__ ljv = (float4*)(out + NN);

    const int nvec   = NN / 4;
    const int tid    = blockIdx.x * blockDim.x + threadIdx.x;
    const int stride = gridDim.x * blockDim.x;

    for (int i = tid; i < nvec; i += stride) {
        float4 xx = xv[i];
        float4 zo, lo;
        rqs1(xx.x, c1, c2, c3, c4, t0, t1, zo.x, lo.x);
        rqs1(xx.y, c1, c2, c3, c4, t0, t1, zo.y, lo.y);
        rqs1(xx.z, c1, c2, c3, c4, t0, t1, zo.z, lo.z);
        rqs1(xx.w, c1, c2, c3, c4, t0, t1, zo.w, lo.w);
        zv[i]  = zo;
        ljv[i] = lo;
    }
}

extern "C" void kernel_launch(void* const* d_in, const int* in_sizes, int n_in,
                              void* d_out, int out_size, void* d_ws, size_t ws_size,
                              hipStream_t stream) {
    const float* x      = (const float*)d_in[0];
    const float* params = (const float*)d_in[1];
    float* out          = (float*)d_out;
    dim3 grid(2048), block(256);
    rqs_kernel<<<grid, block, 0, stream>>>(x, params, out);
}